// Round 17
// baseline (88.626 us; speedup 1.0000x reference)
//
#include <hip/hip_runtime.h>
#include <hip/hip_fp16.h>
#include <math.h>

#define BB 16
#define CIN 64
#define HH 64
#define WW 64
#define COUT 128
#define HW 4096          // HH*WW
#define CK 576           // CIN*9
#define VROW 612         // val row stride (f16): 9 taps * 68 (64 + 4 pad)

typedef _Float16 f16;
typedef __attribute__((ext_vector_type(8))) _Float16 f16x8;
typedef __attribute__((ext_vector_type(8))) short short8;
typedef __attribute__((ext_vector_type(4))) short short4v;
typedef __attribute__((ext_vector_type(4))) float f32x4;

// ---- workspace layout (float indices) ----
#define WT_OFF    0                         // wt2: 73728 f16 = 36864 floats
#define WPM_OFF   36864                     // wpm2: 18432 f16 = 9216 floats
#define XH_OFF    46080                     // xh: 4194304 f16 = 2097152 floats
#define YB_OFF    2143232                   // yb: 8388608 f16 = 4194304 floats
#define SAB_OFF   6337536                   // 256 floats
#define STAT_OFF  6337792                   // 64 slots * 256 floats

union U8h { short8 s; __half2 h[4]; f16x8 f; };
union U4h { short4v s; __half2 h[2]; };
union UWh { unsigned u; __half2 h; };

// ---------------------------------------------------------------------------
// Kernel A: FUSED  (blocks <1024) x NCHW -> NHWC f16  |  (blocks >=1024) weight pack
__global__ __launch_bounds__(256) void k_prep(const float* __restrict__ x,
                                              const float* __restrict__ wd,
                                              const float* __restrict__ wp,
                                              const float* __restrict__ wm,
                                              f16* __restrict__ xh,
                                              f16* __restrict__ wt2,
                                              f16* __restrict__ wpm2) {
    const int blk = blockIdx.x;
    if (blk < 1024) {
        __shared__ float t[64][65];
        const int b    = blk >> 6;
        const int pos0 = (blk & 63) << 6;
        {
            const int c4 = threadIdx.x & 15;
            const int cc = threadIdx.x >> 4;
#pragma unroll
            for (int j = 0; j < 4; ++j) {
                int c = cc + j * 16;
                float4 v = *(const float4*)&x[((size_t)(b * CIN + c)) * HW + pos0 + c4 * 4];
                t[c][c4 * 4 + 0] = v.x;
                t[c][c4 * 4 + 1] = v.y;
                t[c][c4 * 4 + 2] = v.z;
                t[c][c4 * 4 + 3] = v.w;
            }
        }
        __syncthreads();
        {
            const int a2 = (threadIdx.x & 31) * 2;
            const int q  = threadIdx.x >> 5;
#pragma unroll
            for (int i = 0; i < 8; ++i) {
                int p = i * 8 + q;
                __half2 hv = __halves2half2(__float2half(t[a2][p]),
                                            __float2half(t[a2 + 1][p]));
                UWh u; u.h = hv;
                *(unsigned*)&xh[((size_t)b * HW + pos0 + p) * CIN + a2] = u.u;
            }
        }
        return;
    }
    int i = (blk - 1024) * 256 + threadIdx.x;
    if (i < 18 * 128 * 32) {
        int kc  = i >> 12;
        int rem = i & 4095;
        int co  = rem >> 5;
        int kl  = rem & 31;
        int kk  = kc * 32 + kl;
        int k   = kk >> 6;
        int c   = kk & 63;
        wt2[i] = (f16)wd[co * CK + c * 9 + k];
        return;
    }
    i -= 18 * 128 * 32;
    if (i < 18 * 32 * 32) {
        int kc  = i >> 10;
        int rem = i & 1023;
        int t   = rem >> 5;
        int kl  = rem & 31;
        int kk  = kc * 32 + kl;
        int k   = kk >> 6;
        int c   = kk & 63;
        float v = 0.f;
        if (t < 18)      v = wp[t * CK + c * 9 + k];
        else if (t < 27) v = wm[(t - 18) * CK + c * 9 + k];
        wpm2[i] = (f16)v;
    }
}

// ---------------------------------------------------------------------------
// conv A-fragment loader (shifted-window NHWC patch, f16)
__device__ __forceinline__ f16x8 conv_a(const f16* __restrict__ xb,
                                        int ho, int wo, int lk, int kc) {
    const int k  = kc >> 1;
    const int c0 = (kc & 1) * 32 + lk * 8;
    const int yy = ho - 1 + k / 3;
    const int xx = wo - 1 + k % 3;
    const bool valid = ((unsigned)yy < 64u) & ((unsigned)xx < 64u);
    const int yyc = min(max(yy, 0), 63);
    const int xxc = min(max(xx, 0), 63);
    f16x8 a = *(const f16x8*)&xb[(((yyc << 6) + xxc) << 6) + c0];
    if (!valid) a = (f16x8)0;
    return a;
}

// ---------------------------------------------------------------------------
// Kernel 2: FUSED conv + deform + BN partials. MPB=32, 512 threads (8 waves).
// LDS trimmed to <50KB -> 3 blocks/CU; s_setprio around MFMA clusters.
#define MPB 32
__global__ __launch_bounds__(512) void k_deform(const f16* __restrict__ xh,
                                                const f16* __restrict__ wt2,
                                                const f16* __restrict__ wpm2,
                                                const float* __restrict__ bp,
                                                const float* __restrict__ bm,
                                                const float* __restrict__ bd,
                                                f16* __restrict__ yb,
                                                float* __restrict__ gstat) {
    __shared__ f16       val[MPB * VROW];    // 39168 B  [p][k*68 + c]
    __shared__ float     s_pm2[2][27][33];   // 7128 B   conv partials [kh][t][p], t<27
    __shared__ unsigned  s_yx[MPB * 9];      // 1152 B
    __shared__ unsigned short s_w[MPB * 9 * 4]; // 2304 B half weights (expand on read)
    // total 49752 B -> 3 blocks/CU (149.3KB of 160KB)

    const int bid  = blockIdx.x;                       // 2048
    const int swz  = (bid & 7) * 256 + (bid >> 3);     // XCD-chunked
    const int pos0 = swz * MPB;
    const int b   = pos0 >> 12;
    const int ho  = (pos0 >> 6) & 63;
    const int wo0 = pos0 & 63;                         // 0 or 32
    const int tid = threadIdx.x;
    const int wv   = tid >> 6;
    const int lane = tid & 63;
    const int l15  = lane & 15;
    const int lk   = lane >> 4;

    const f16* xb = xh + (size_t)b * HW * CIN;

    // ---- phase 0: offset/mask conv, all 8 waves, K-split ----
    {
        const int mw = wv & 1;          // position half
        const int nw = (wv >> 1) & 1;   // channel half
        const int kh = wv >> 2;         // K half
        const int t  = nw * 16 + l15;   // out channel 0..31 (>=27 uses zero rows)
        const f16* wr = wpm2 + t * 32 + lk * 8;
        const int wo = wo0 + mw * 16 + l15;
        f32x4 acc = (f32x4)(0.f);
        __builtin_amdgcn_s_setprio(1);
#pragma unroll
        for (int kc = kh * 9; kc < kh * 9 + 9; ++kc) {
            f16x8 a  = conv_a(xb, ho, wo, lk, kc);
            f16x8 bf = *(const f16x8*)&wr[kc * 1024];
            acc = __builtin_amdgcn_mfma_f32_16x16x32_f16(a, bf, acc, 0, 0, 0);
        }
        __builtin_amdgcn_s_setprio(0);
        if (t < 27) {
#pragma unroll
            for (int j = 0; j < 4; ++j)
                s_pm2[kh][t][mw * 16 + lk * 4 + j] = acc[j];
        }
    }
    __syncthreads();

    // ---- phase 1: sampling params (32 pos x 9 taps = 288) ----
    if (tid < MPB * 9) {
        int k = tid >> 5;               // 0..8
        int p = tid & 31;
        int wo = wo0 + p;
        float dy = s_pm2[0][2 * k    ][p] + s_pm2[1][2 * k    ][p] + bp[2 * k];
        float dx = s_pm2[0][2 * k + 1][p] + s_pm2[1][2 * k + 1][p] + bp[2 * k + 1];
        float mm = s_pm2[0][18 + k   ][p] + s_pm2[1][18 + k   ][p] + bm[k];
        float m  = 1.f / (1.f + expf(-mm));
        float py = (float)(ho - 1 + k / 3) + dy;
        float px = (float)(wo - 1 + k % 3) + dx;
        float fy = floorf(py), fx = floorf(px);
        float ly = py - fy, lx = px - fx;
        int y0 = (int)fy, x0 = (int)fx;
        int y1 = y0 + 1, x1 = x0 + 1;
        float vy0 = ((unsigned)y0 < 64u) ? 1.f : 0.f;
        float vy1 = ((unsigned)y1 < 64u) ? 1.f : 0.f;
        float vx0 = ((unsigned)x0 < 64u) ? 1.f : 0.f;
        float vx1 = ((unsigned)x1 < 64u) ? 1.f : 0.f;
        int y0c = min(max(y0, 0), 63), y1c = min(max(y1, 0), 63);
        int x0c = min(max(x0, 0), 63), x1c = min(max(x1, 0), 63);
        int tt = p * 9 + k;
        s_yx[tt] = (unsigned)y0c | ((unsigned)y1c << 8) | ((unsigned)x0c << 16) | ((unsigned)x1c << 24);
        s_w[tt * 4 + 0] = __half_as_ushort(__float2half((1.f - ly) * (1.f - lx) * m * vy0 * vx0));
        s_w[tt * 4 + 1] = __half_as_ushort(__float2half((1.f - ly) * lx * m * vy0 * vx1));
        s_w[tt * 4 + 2] = __half_as_ushort(__float2half(ly * (1.f - lx) * m * vy1 * vx0));
        s_w[tt * 4 + 3] = __half_as_ushort(__float2half(ly * lx * m * vy1 * vx1));
    }
    __syncthreads();

    // ---- phase 2: gather; 64 groups x 8 lanes; packed __hfma2 blend ----
    {
        const int g  = tid >> 3;        // 0..63 groups
        const int li = tid & 7;
        const int c0 = li * 8;
#pragma unroll
        for (int it = 0; it < 5; ++it) {
            int pr = it * 64 + g;       // 0..319, guard 288
            if (pr < MPB * 9) {
                unsigned yx = s_yx[pr];
                int y0 = yx & 255, y1 = (yx >> 8) & 255;
                int x0 = (yx >> 16) & 255, x1 = yx >> 24;
                UWh w0u, w1u, w2u, w3u;
                w0u.u = (unsigned)s_w[pr * 4 + 0] * 0x10001u;
                w1u.u = (unsigned)s_w[pr * 4 + 1] * 0x10001u;
                w2u.u = (unsigned)s_w[pr * 4 + 2] * 0x10001u;
                w3u.u = (unsigned)s_w[pr * 4 + 3] * 0x10001u;
                U8h v00, v01, v10, v11, o;
                v00.s = *(const short8*)&xb[(((y0 << 6) + x0) << 6) + c0];
                v01.s = *(const short8*)&xb[(((y0 << 6) + x1) << 6) + c0];
                v10.s = *(const short8*)&xb[(((y1 << 6) + x0) << 6) + c0];
                v11.s = *(const short8*)&xb[(((y1 << 6) + x1) << 6) + c0];
                int p = pr / 9, k = pr - p * 9;
#pragma unroll
                for (int h2 = 0; h2 < 4; ++h2) {
                    o.h[h2] = __hfma2(v00.h[h2], w0u.h,
                              __hfma2(v01.h[h2], w1u.h,
                              __hfma2(v10.h[h2], w2u.h,
                              __hmul2(v11.h[h2], w3u.h))));
                }
                *(short8*)&val[p * VROW + k * 68 + c0] = o.s;   // ds_write_b128
            }
        }
    }
    __syncthreads();

    // ---- phase 3: wave owns co = wv*16..+15; B read once per block ----
    f32x4 acc0 = (f32x4)(0.f);      // positions 0..15
    f32x4 acc1 = (f32x4)(0.f);      // positions 16..31
    const f16* wq = wt2 + (size_t)(wv * 16 + l15) * 32 + lk * 8;
    const int arow0 = l15 * VROW + lk * 8;
    const int arow1 = (l15 + 16) * VROW + lk * 8;
    __builtin_amdgcn_s_setprio(1);
#pragma unroll
    for (int kc = 0; kc < 18; ++kc) {
        const int koff = (kc >> 1) * 68 + (kc & 1) * 32;
        f16x8 a0 = *(const f16x8*)&val[arow0 + koff];
        f16x8 a1 = *(const f16x8*)&val[arow1 + koff];
        f16x8 bf = *(const f16x8*)&wq[kc * 4096];
        acc0 = __builtin_amdgcn_mfma_f32_16x16x32_f16(a0, bf, acc0, 0, 0, 0);
        acc1 = __builtin_amdgcn_mfma_f32_16x16x32_f16(a1, bf, acc1, 0, 0, 0);
    }
    __builtin_amdgcn_s_setprio(0);

    // ---- epilogue: f16 y writes (+bias) and BN partials (64-slot spread) ----
    const int co = wv * 16 + l15;
    {
        float bias = bd[co];
        f16* ybp = yb + ((size_t)(b * COUT + co)) * HW + ho * WW + wo0;
        U4h o0, o1;
        o0.h[0] = __halves2half2(__float2half(acc0[0] + bias), __float2half(acc0[1] + bias));
        o0.h[1] = __halves2half2(__float2half(acc0[2] + bias), __float2half(acc0[3] + bias));
        *(short4v*)&ybp[lk * 4] = o0.s;
        o1.h[0] = __halves2half2(__float2half(acc1[0] + bias), __float2half(acc1[1] + bias));
        o1.h[1] = __halves2half2(__float2half(acc1[2] + bias), __float2half(acc1[3] + bias));
        *(short4v*)&ybp[16 + lk * 4] = o1.s;
    }
    float s0 = acc0[0] + acc0[1] + acc0[2] + acc0[3]
             + acc1[0] + acc1[1] + acc1[2] + acc1[3];
    float q0 = acc0[0]*acc0[0] + acc0[1]*acc0[1] + acc0[2]*acc0[2] + acc0[3]*acc0[3]
             + acc1[0]*acc1[0] + acc1[1]*acc1[1] + acc1[2]*acc1[2] + acc1[3]*acc1[3];
    s0 += __shfl_xor(s0, 16); s0 += __shfl_xor(s0, 32);
    q0 += __shfl_xor(q0, 16); q0 += __shfl_xor(q0, 32);
    if (lane < 16) {
        float* slot = gstat + (bid & 63) * 256;
        atomicAdd(&slot[wv * 16 + lane],       s0);
        atomicAdd(&slot[128 + wv * 16 + lane], q0);
    }
}

// ---------------------------------------------------------------------------
// Kernel 3: finalize BN scale/shift (reduce 64 slots, ILP-4)
__global__ __launch_bounds__(128) void k_finalize(const float* __restrict__ gstat,
                                                  const float* __restrict__ bd,
                                                  const float* __restrict__ gamma,
                                                  const float* __restrict__ beta,
                                                  float* __restrict__ sAB) {
    int c = threadIdx.x;
    float sa[4] = {0.f, 0.f, 0.f, 0.f};
    float qa[4] = {0.f, 0.f, 0.f, 0.f};
#pragma unroll
    for (int sl = 0; sl < 64; sl += 4) {
#pragma unroll
        for (int j = 0; j < 4; ++j) {
            sa[j] += gstat[(sl + j) * 256 + c];
            qa[j] += gstat[(sl + j) * 256 + 128 + c];
        }
    }
    float s = (sa[0] + sa[1]) + (sa[2] + sa[3]);
    float q = (qa[0] + qa[1]) + (qa[2] + qa[3]);
    const float invN = 1.f / (float)(BB * HW);
    float mean_acc = s * invN;
    float var = q * invN - mean_acc * mean_acc;
    float mean_y = mean_acc + bd[c];
    float A = gamma[c] * rsqrtf(var + 1e-5f);
    sAB[c]       = A;
    sAB[128 + c] = beta[c] - mean_y * A;
}

// ---------------------------------------------------------------------------
// Kernel 4: normalize + exact GELU. Reads f16 y (16B/lane), writes f32 d_out.
__global__ __launch_bounds__(256) void k_norm_gelu(const f16* __restrict__ yb,
                                                   const float* __restrict__ sAB,
                                                   float* __restrict__ out) {
    int i8 = blockIdx.x * 256 + threadIdx.x;        // 1048576 groups of 8
    if (i8 >= (BB * COUT * HW) / 8) return;
    int c = (i8 >> 9) & 127;
    float A  = sAB[c];
    float Bc = sAB[128 + c];
    f16x8 v = *(const f16x8*)&yb[(size_t)i8 * 8];
    float4 r0, r1;
    float t;
    t = (float)v[0] * A + Bc; r0.x = 0.5f * t * (1.f + erff(t * 0.70710678118654752f));
    t = (float)v[1] * A + Bc; r0.y = 0.5f * t * (1.f + erff(t * 0.70710678118654752f));
    t = (float)v[2] * A + Bc; r0.z = 0.5f * t * (1.f + erff(t * 0.70710678118654752f));
    t = (float)v[3] * A + Bc; r0.w = 0.5f * t * (1.f + erff(t * 0.70710678118654752f));
    t = (float)v[4] * A + Bc; r1.x = 0.5f * t * (1.f + erff(t * 0.70710678118654752f));
    t = (float)v[5] * A + Bc; r1.y = 0.5f * t * (1.f + erff(t * 0.70710678118654752f));
    t = (float)v[6] * A + Bc; r1.z = 0.5f * t * (1.f + erff(t * 0.70710678118654752f));
    t = (float)v[7] * A + Bc; r1.w = 0.5f * t * (1.f + erff(t * 0.70710678118654752f));
    *(float4*)&out[(size_t)i8 * 8]     = r0;
    *(float4*)&out[(size_t)i8 * 8 + 4] = r1;
}

// ---------------------------------------------------------------------------
extern "C" void kernel_launch(void* const* d_in, const int* in_sizes, int n_in,
                              void* d_out, int out_size, void* d_ws, size_t ws_size,
                              hipStream_t stream) {
    const float* x     = (const float*)d_in[0];
    const float* w_p   = (const float*)d_in[1];
    const float* b_p   = (const float*)d_in[2];
    const float* w_m   = (const float*)d_in[3];
    const float* b_m   = (const float*)d_in[4];
    const float* w_d   = (const float*)d_in[5];
    const float* b_d   = (const float*)d_in[6];
    const float* gamma = (const float*)d_in[7];
    const float* beta  = (const float*)d_in[8];
    float* ws  = (float*)d_ws;
    float* out = (float*)d_out;

    f16*  wt2  = (f16*)(ws + WT_OFF);
    f16*  wpm2 = (f16*)(ws + WPM_OFF);
    f16*  xh   = (f16*)(ws + XH_OFF);
    f16*  yb   = (f16*)(ws + YB_OFF);
    float* sAB  = ws + SAB_OFF;
    float* gstat= ws + STAT_OFF;

    hipMemsetAsync(gstat, 0, 64 * 256 * sizeof(float), stream);
    k_prep<<<dim3(1024 + 360), dim3(256), 0, stream>>>(x, w_d, w_p, w_m, xh, wt2, wpm2);
    k_deform<<<dim3(BB * HW / MPB), dim3(512), 0, stream>>>(xh, wt2, wpm2, b_p, b_m, b_d, yb, gstat);
    k_finalize<<<dim3(1), dim3(128), 0, stream>>>(gstat, b_d, gamma, beta, sAB);
    k_norm_gelu<<<dim3(BB * COUT * HW / 8 / 256), dim3(256), 0, stream>>>(yb, sAB, out);
}

// Round 18
// 83.410 us; speedup vs baseline: 1.0625x; 1.0625x over previous
//
#include <hip/hip_runtime.h>
#include <hip/hip_fp16.h>
#include <math.h>

#define BB 16
#define CIN 64
#define HH 64
#define WW 64
#define COUT 128
#define HW 4096          // HH*WW
#define CK 576           // CIN*9
#define VROW 612         // val row stride (f16): 9 taps * 68 (64 + 4 pad)

typedef _Float16 f16;
typedef __attribute__((ext_vector_type(8))) _Float16 f16x8;
typedef __attribute__((ext_vector_type(8))) short short8;
typedef __attribute__((ext_vector_type(4))) short short4v;
typedef __attribute__((ext_vector_type(4))) float f32x4;

// ---- workspace layout (float indices) ----
#define WT_OFF    0                         // wt2: 73728 f16 = 36864 floats
#define WPM_OFF   36864                     // wpm2: 18432 f16 = 9216 floats
#define XH_OFF    46080                     // xh: 4194304 f16 = 2097152 floats
#define YB_OFF    2143232                   // yb: 8388608 f16 = 4194304 floats
#define SAB_OFF   6337536                   // 256 floats
#define STAT_OFF  6337792                   // 64 slots * 256 floats

union U8h { short8 s; __half2 h[4]; f16x8 f; };
union U4h { short4v s; __half2 h[2]; };
union UWh { unsigned u; __half2 h; };

// ---------------------------------------------------------------------------
// Kernel A: FUSED  (blocks <1024) x NCHW -> NHWC f16  |  (blocks >=1024) weight pack
__global__ __launch_bounds__(256) void k_prep(const float* __restrict__ x,
                                              const float* __restrict__ wd,
                                              const float* __restrict__ wp,
                                              const float* __restrict__ wm,
                                              f16* __restrict__ xh,
                                              f16* __restrict__ wt2,
                                              f16* __restrict__ wpm2) {
    const int blk = blockIdx.x;
    if (blk < 1024) {
        __shared__ float t[64][65];
        const int b    = blk >> 6;
        const int pos0 = (blk & 63) << 6;
        // read: float4 along positions
        {
            const int c4 = threadIdx.x & 15;       // position quad
            const int cc = threadIdx.x >> 4;       // 16 channel groups
#pragma unroll
            for (int j = 0; j < 4; ++j) {
                int c = cc + j * 16;
                float4 v = *(const float4*)&x[((size_t)(b * CIN + c)) * HW + pos0 + c4 * 4];
                t[c][c4 * 4 + 0] = v.x;
                t[c][c4 * 4 + 1] = v.y;
                t[c][c4 * 4 + 2] = v.z;
                t[c][c4 * 4 + 3] = v.w;
            }
        }
        __syncthreads();
        // write: packed half2 (2 channels/lane)
        {
            const int a2 = (threadIdx.x & 31) * 2;
            const int q  = threadIdx.x >> 5;       // 0..7
#pragma unroll
            for (int i = 0; i < 8; ++i) {
                int p = i * 8 + q;
                __half2 hv = __halves2half2(__float2half(t[a2][p]),
                                            __float2half(t[a2 + 1][p]));
                UWh u; u.h = hv;
                *(unsigned*)&xh[((size_t)b * HW + pos0 + p) * CIN + a2] = u.u;
            }
        }
        return;
    }
    int i = (blk - 1024) * 256 + threadIdx.x;       // 360 blocks * 256 = 92160
    if (i < 18 * 128 * 32) {
        int kc  = i >> 12;
        int rem = i & 4095;
        int co  = rem >> 5;
        int kl  = rem & 31;
        int kk  = kc * 32 + kl;
        int k   = kk >> 6;
        int c   = kk & 63;
        wt2[i] = (f16)wd[co * CK + c * 9 + k];
        return;
    }
    i -= 18 * 128 * 32;
    if (i < 18 * 32 * 32) {
        int kc  = i >> 10;
        int rem = i & 1023;
        int t   = rem >> 5;
        int kl  = rem & 31;
        int kk  = kc * 32 + kl;
        int k   = kk >> 6;
        int c   = kk & 63;
        float v = 0.f;
        if (t < 18)      v = wp[t * CK + c * 9 + k];
        else if (t < 27) v = wm[(t - 18) * CK + c * 9 + k];
        wpm2[i] = (f16)v;
    }
}

// ---------------------------------------------------------------------------
// conv A-fragment loader (shifted-window NHWC patch, f16)
__device__ __forceinline__ f16x8 conv_a(const f16* __restrict__ xb,
                                        int ho, int wo, int lk, int kc) {
    const int k  = kc >> 1;
    const int c0 = (kc & 1) * 32 + lk * 8;
    const int yy = ho - 1 + k / 3;
    const int xx = wo - 1 + k % 3;
    const bool valid = ((unsigned)yy < 64u) & ((unsigned)xx < 64u);
    const int yyc = min(max(yy, 0), 63);
    const int xxc = min(max(xx, 0), 63);
    f16x8 a = *(const f16x8*)&xb[(((yyc << 6) + xxc) << 6) + c0];
    if (!valid) a = (f16x8)0;
    return a;
}

// ---------------------------------------------------------------------------
// Kernel 2: FUSED conv + deform + BN partials. MPB=32, 512 threads (8 waves).
// f16 pipeline: packed __hfma2 blend, mfma_f32_16x16x32_f16.
#define MPB 32
__global__ __launch_bounds__(512) void k_deform(const f16* __restrict__ xh,
                                                const f16* __restrict__ wt2,
                                                const f16* __restrict__ wpm2,
                                                const float* __restrict__ bp,
                                                const float* __restrict__ bm,
                                                const float* __restrict__ bd,
                                                f16* __restrict__ yb,
                                                float* __restrict__ gstat) {
    __shared__ f16       val[MPB * VROW];    // 39168 B  [p][k*68 + c]
    __shared__ float     s_pm2[2][28][33];   // 7392 B   conv partials [kh][t][p], t<28
    __shared__ unsigned  s_yx[MPB * 9];      // 1152 B
    __shared__ unsigned  s_w[MPB * 9 * 4];   // 4608 B   half2-broadcast weights
    // total 52320 B

    const int bid  = blockIdx.x;                       // 2048
    const int swz  = (bid & 7) * 256 + (bid >> 3);     // XCD-chunked
    const int pos0 = swz * MPB;
    const int b   = pos0 >> 12;
    const int ho  = (pos0 >> 6) & 63;
    const int wo0 = pos0 & 63;                         // 0 or 32
    const int tid = threadIdx.x;
    const int wv   = tid >> 6;
    const int lane = tid & 63;
    const int l15  = lane & 15;
    const int lk   = lane >> 4;

    const f16* xb = xh + (size_t)b * HW * CIN;

    // ---- phase 0: offset/mask conv, all 8 waves, K-split ----
    {
        const int mw = wv & 1;          // position half
        const int nw = (wv >> 1) & 1;   // channel half
        const int kh = wv >> 2;         // K half
        const int t  = nw * 16 + l15;   // out channel 0..31 (>=27 uses zero rows)
        const f16* wr = wpm2 + t * 32 + lk * 8;
        const int wo = wo0 + mw * 16 + l15;
        f32x4 acc = (f32x4)(0.f);
#pragma unroll
        for (int kc = kh * 9; kc < kh * 9 + 9; ++kc) {
            f16x8 a  = conv_a(xb, ho, wo, lk, kc);
            f16x8 bf = *(const f16x8*)&wr[kc * 1024];
            acc = __builtin_amdgcn_mfma_f32_16x16x32_f16(a, bf, acc, 0, 0, 0);
        }
        if (t < 28) {
#pragma unroll
            for (int j = 0; j < 4; ++j)
                s_pm2[kh][t][mw * 16 + lk * 4 + j] = acc[j];
        }
    }
    __syncthreads();

    // ---- phase 1: sampling params (32 pos x 9 taps = 288) ----
    if (tid < MPB * 9) {
        int k = tid >> 5;               // 0..8
        int p = tid & 31;
        int wo = wo0 + p;
        float dy = s_pm2[0][2 * k    ][p] + s_pm2[1][2 * k    ][p] + bp[2 * k];
        float dx = s_pm2[0][2 * k + 1][p] + s_pm2[1][2 * k + 1][p] + bp[2 * k + 1];
        float mm = s_pm2[0][18 + k   ][p] + s_pm2[1][18 + k   ][p] + bm[k];
        float m  = 1.f / (1.f + expf(-mm));
        float py = (float)(ho - 1 + k / 3) + dy;
        float px = (float)(wo - 1 + k % 3) + dx;
        float fy = floorf(py), fx = floorf(px);
        float ly = py - fy, lx = px - fx;
        int y0 = (int)fy, x0 = (int)fx;
        int y1 = y0 + 1, x1 = x0 + 1;
        float vy0 = ((unsigned)y0 < 64u) ? 1.f : 0.f;
        float vy1 = ((unsigned)y1 < 64u) ? 1.f : 0.f;
        float vx0 = ((unsigned)x0 < 64u) ? 1.f : 0.f;
        float vx1 = ((unsigned)x1 < 64u) ? 1.f : 0.f;
        int y0c = min(max(y0, 0), 63), y1c = min(max(y1, 0), 63);
        int x0c = min(max(x0, 0), 63), x1c = min(max(x1, 0), 63);
        int tt = p * 9 + k;
        s_yx[tt] = (unsigned)y0c | ((unsigned)y1c << 8) | ((unsigned)x0c << 16) | ((unsigned)x1c << 24);
        float w0 = (1.f - ly) * (1.f - lx) * m * vy0 * vx0;
        float w1 = (1.f - ly) * lx * m * vy0 * vx1;
        float w2 = ly * (1.f - lx) * m * vy1 * vx0;
        float w3 = ly * lx * m * vy1 * vx1;
        s_w[tt * 4 + 0] = (unsigned)__half_as_ushort(__float2half(w0)) * 0x10001u;
        s_w[tt * 4 + 1] = (unsigned)__half_as_ushort(__float2half(w1)) * 0x10001u;
        s_w[tt * 4 + 2] = (unsigned)__half_as_ushort(__float2half(w2)) * 0x10001u;
        s_w[tt * 4 + 3] = (unsigned)__half_as_ushort(__float2half(w3)) * 0x10001u;
    }
    __syncthreads();

    // ---- phase 2: gather; 64 groups x 8 lanes; packed __hfma2 blend ----
    {
        const int g  = tid >> 3;        // 0..63 groups
        const int li = tid & 7;
        const int c0 = li * 8;
#pragma unroll
        for (int it = 0; it < 5; ++it) {
            int pr = it * 64 + g;       // 0..319, guard 288
            if (pr < MPB * 9) {
                unsigned yx = s_yx[pr];
                int y0 = yx & 255, y1 = (yx >> 8) & 255;
                int x0 = (yx >> 16) & 255, x1 = yx >> 24;
                UWh w0u, w1u, w2u, w3u;
                w0u.u = s_w[pr * 4 + 0];
                w1u.u = s_w[pr * 4 + 1];
                w2u.u = s_w[pr * 4 + 2];
                w3u.u = s_w[pr * 4 + 3];
                U8h v00, v01, v10, v11, o;
                v00.s = *(const short8*)&xb[(((y0 << 6) + x0) << 6) + c0];
                v01.s = *(const short8*)&xb[(((y0 << 6) + x1) << 6) + c0];
                v10.s = *(const short8*)&xb[(((y1 << 6) + x0) << 6) + c0];
                v11.s = *(const short8*)&xb[(((y1 << 6) + x1) << 6) + c0];
                int p = pr / 9, k = pr - p * 9;
#pragma unroll
                for (int h2 = 0; h2 < 4; ++h2) {
                    o.h[h2] = __hfma2(v00.h[h2], w0u.h,
                              __hfma2(v01.h[h2], w1u.h,
                              __hfma2(v10.h[h2], w2u.h,
                              __hmul2(v11.h[h2], w3u.h))));
                }
                *(short8*)&val[p * VROW + k * 68 + c0] = o.s;   // ds_write_b128
            }
        }
    }
    __syncthreads();

    // ---- phase 3: wave owns co = wv*16..+15; B read once per block ----
    f32x4 acc0 = (f32x4)(0.f);      // positions 0..15
    f32x4 acc1 = (f32x4)(0.f);      // positions 16..31
    const f16* wq = wt2 + (size_t)(wv * 16 + l15) * 32 + lk * 8;
    const int arow0 = l15 * VROW + lk * 8;
    const int arow1 = (l15 + 16) * VROW + lk * 8;
#pragma unroll
    for (int kc = 0; kc < 18; ++kc) {
        const int koff = (kc >> 1) * 68 + (kc & 1) * 32;
        f16x8 a0 = *(const f16x8*)&val[arow0 + koff];
        f16x8 a1 = *(const f16x8*)&val[arow1 + koff];
        f16x8 bf = *(const f16x8*)&wq[kc * 4096];
        acc0 = __builtin_amdgcn_mfma_f32_16x16x32_f16(a0, bf, acc0, 0, 0, 0);
        acc1 = __builtin_amdgcn_mfma_f32_16x16x32_f16(a1, bf, acc1, 0, 0, 0);
    }

    // ---- epilogue: f16 y writes (+bias) and BN partials (64-slot spread) ----
    const int co = wv * 16 + l15;
    {
        float bias = bd[co];
        f16* ybp = yb + ((size_t)(b * COUT + co)) * HW + ho * WW + wo0;
        U4h o0, o1;
        o0.h[0] = __halves2half2(__float2half(acc0[0] + bias), __float2half(acc0[1] + bias));
        o0.h[1] = __halves2half2(__float2half(acc0[2] + bias), __float2half(acc0[3] + bias));
        *(short4v*)&ybp[lk * 4] = o0.s;
        o1.h[0] = __halves2half2(__float2half(acc1[0] + bias), __float2half(acc1[1] + bias));
        o1.h[1] = __halves2half2(__float2half(acc1[2] + bias), __float2half(acc1[3] + bias));
        *(short4v*)&ybp[16 + lk * 4] = o1.s;
    }
    float s0 = acc0[0] + acc0[1] + acc0[2] + acc0[3]
             + acc1[0] + acc1[1] + acc1[2] + acc1[3];
    float q0 = acc0[0]*acc0[0] + acc0[1]*acc0[1] + acc0[2]*acc0[2] + acc0[3]*acc0[3]
             + acc1[0]*acc1[0] + acc1[1]*acc1[1] + acc1[2]*acc1[2] + acc1[3]*acc1[3];
    s0 += __shfl_xor(s0, 16); s0 += __shfl_xor(s0, 32);
    q0 += __shfl_xor(q0, 16); q0 += __shfl_xor(q0, 32);
    if (lane < 16) {
        float* slot = gstat + (bid & 63) * 256;
        atomicAdd(&slot[wv * 16 + lane],       s0);
        atomicAdd(&slot[128 + wv * 16 + lane], q0);
    }
}

// ---------------------------------------------------------------------------
// Kernel 3: finalize BN scale/shift (reduce 64 slots, ILP-4)
__global__ __launch_bounds__(128) void k_finalize(const float* __restrict__ gstat,
                                                  const float* __restrict__ bd,
                                                  const float* __restrict__ gamma,
                                                  const float* __restrict__ beta,
                                                  float* __restrict__ sAB) {
    int c = threadIdx.x;
    float sa[4] = {0.f, 0.f, 0.f, 0.f};
    float qa[4] = {0.f, 0.f, 0.f, 0.f};
#pragma unroll
    for (int sl = 0; sl < 64; sl += 4) {
#pragma unroll
        for (int j = 0; j < 4; ++j) {
            sa[j] += gstat[(sl + j) * 256 + c];
            qa[j] += gstat[(sl + j) * 256 + 128 + c];
        }
    }
    float s = (sa[0] + sa[1]) + (sa[2] + sa[3]);
    float q = (qa[0] + qa[1]) + (qa[2] + qa[3]);
    const float invN = 1.f / (float)(BB * HW);
    float mean_acc = s * invN;
    float var = q * invN - mean_acc * mean_acc;
    float mean_y = mean_acc + bd[c];
    float A = gamma[c] * rsqrtf(var + 1e-5f);
    sAB[c]       = A;
    sAB[128 + c] = beta[c] - mean_y * A;
}

// ---------------------------------------------------------------------------
// Kernel 4: normalize + exact GELU. Reads f16 y (16B/lane), writes f32 d_out.
__global__ __launch_bounds__(256) void k_norm_gelu(const f16* __restrict__ yb,
                                                   const float* __restrict__ sAB,
                                                   float* __restrict__ out) {
    int i8 = blockIdx.x * 256 + threadIdx.x;        // 1048576 groups of 8
    if (i8 >= (BB * COUT * HW) / 8) return;
    int c = (i8 >> 9) & 127;
    float A  = sAB[c];
    float Bc = sAB[128 + c];
    f16x8 v = *(const f16x8*)&yb[(size_t)i8 * 8];
    float4 r0, r1;
    float t;
    t = (float)v[0] * A + Bc; r0.x = 0.5f * t * (1.f + erff(t * 0.70710678118654752f));
    t = (float)v[1] * A + Bc; r0.y = 0.5f * t * (1.f + erff(t * 0.70710678118654752f));
    t = (float)v[2] * A + Bc; r0.z = 0.5f * t * (1.f + erff(t * 0.70710678118654752f));
    t = (float)v[3] * A + Bc; r0.w = 0.5f * t * (1.f + erff(t * 0.70710678118654752f));
    t = (float)v[4] * A + Bc; r1.x = 0.5f * t * (1.f + erff(t * 0.70710678118654752f));
    t = (float)v[5] * A + Bc; r1.y = 0.5f * t * (1.f + erff(t * 0.70710678118654752f));
    t = (float)v[6] * A + Bc; r1.z = 0.5f * t * (1.f + erff(t * 0.70710678118654752f));
    t = (float)v[7] * A + Bc; r1.w = 0.5f * t * (1.f + erff(t * 0.70710678118654752f));
    *(float4*)&out[(size_t)i8 * 8]     = r0;
    *(float4*)&out[(size_t)i8 * 8 + 4] = r1;
}

// ---------------------------------------------------------------------------
extern "C" void kernel_launch(void* const* d_in, const int* in_sizes, int n_in,
                              void* d_out, int out_size, void* d_ws, size_t ws_size,
                              hipStream_t stream) {
    const float* x     = (const float*)d_in[0];
    const float* w_p   = (const float*)d_in[1];
    const float* b_p   = (const float*)d_in[2];
    const float* w_m   = (const float*)d_in[3];
    const float* b_m   = (const float*)d_in[4];
    const float* w_d   = (const float*)d_in[5];
    const float* b_d   = (const float*)d_in[6];
    const float* gamma = (const float*)d_in[7];
    const float* beta  = (const float*)d_in[8];
    float* ws  = (float*)d_ws;
    float* out = (float*)d_out;

    f16*  wt2  = (f16*)(ws + WT_OFF);
    f16*  wpm2 = (f16*)(ws + WPM_OFF);
    f16*  xh   = (f16*)(ws + XH_OFF);
    f16*  yb   = (f16*)(ws + YB_OFF);
    float* sAB  = ws + SAB_OFF;
    float* gstat= ws + STAT_OFF;

    hipMemsetAsync(gstat, 0, 64 * 256 * sizeof(float), stream);
    k_prep<<<dim3(1024 + 360), dim3(256), 0, stream>>>(x, w_d, w_p, w_m, xh, wt2, wpm2);
    k_deform<<<dim3(BB * HW / MPB), dim3(512), 0, stream>>>(xh, wt2, wpm2, b_p, b_m, b_d, yb, gstat);
    k_finalize<<<dim3(1), dim3(128), 0, stream>>>(gstat, b_d, gamma, beta, sAB);
    k_norm_gelu<<<dim3(BB * COUT * HW / 8 / 256), dim3(256), 0, stream>>>(yb, sAB, out);
}